// Round 3
// baseline (370.315 us; speedup 1.0000x reference)
//
#include <hip/hip_runtime.h>
#include <math.h>

// ---------------------------------------------------------------------------
// Fastformer encoder layer — Round 10: faithful 8-phase m201 schedule.
//
// R9 post-mortem: 256^2 tile with coarse (2-barrier/K-tile) schedule stays at
// the ~900 TF / 38% MfmaUtil 1-phase plateau (m196-V0). The lever is the
// per-phase interleave (m196: fine 8-phase = +28-41%). R10:
//  * ks-separated LDS regions: A[2 slot][2 ks][256x32], B same ->
//    every phase frees one region -> stage 1 ks-half-event (2 gl2lds) per
//    phase into the just-freed region (all write windows verified).
//  * 8 phases per 2-K-tile iteration, each: {ds_read quadrant frags ||
//    2 gl2lds} -> s_barrier -> sched_barrier -> setprio(1)+16 MFMA+setprio(0)
//    -> s_barrier.
//  * vmcnt(8) at odd phases only (BN=256; vmcnt(6)/phase BN=128); drains
//    only in peeled final waits. Prefetch slack 3-4 phases.
//  * in-row XOR swizzle slot=q^(row&3) (conflict-free b128 frag reads),
//    linear gl2lds dests.
//  * BN=128 4-phase variant for N=1024 GEMMs (96KB LDS, grid 256 = 1/CU).
// ws: h16@0 | kv16/act16@16M | vq@48M | fp16 weights@64M | gk@82M | attn@83M
// ---------------------------------------------------------------------------

#define DM     1024
#define FFH    2048
#define M_TOT  8192

typedef _Float16 f16x8 __attribute__((ext_vector_type(8)));
typedef float    f32x4 __attribute__((ext_vector_type(4)));

__device__ __forceinline__ void gl2lds16(const void* g, void* l) {
    __builtin_amdgcn_global_load_lds(
        (const __attribute__((address_space(1))) void*)g,
        (__attribute__((address_space(3))) void*)l, 16, 0, 0);
}
__device__ __forceinline__ unsigned short f2h(float x) {
    union { _Float16 h; unsigned short u; } c;
    c.h = (_Float16)x;
    return c.u;
}
__device__ __forceinline__ float h2f(unsigned short u) {
    union { unsigned short u; _Float16 h; } c;
    c.u = u;
    return (float)c.h;
}

// ---------------------------------------------------------------------------
// weight cast fp32 -> fp16, plain row-major, fully coalesced.
// ---------------------------------------------------------------------------
__global__ __launch_bounds__(256) void wcast(
    const float* __restrict__ s0, const float* __restrict__ s1,
    const float* __restrict__ s2, const float* __restrict__ s3,
    unsigned short* __restrict__ d0, unsigned short* __restrict__ d1,
    unsigned short* __restrict__ d2, unsigned short* __restrict__ d3)
{
    int i = blockIdx.x * 256 + threadIdx.x;
    const float* s; unsigned short* d;
    if      (i < 262144) {               s = s0; d = d0; }
    else if (i < 393216) { i -= 262144;  s = s1; d = d1; }
    else if (i < 917504) { i -= 393216;  s = s2; d = d2; }
    else                 { i -= 917504;  s = s3; d = d3; }
    const float4 v0 = ((const float4*)(s + (size_t)i * 8))[0];
    const float4 v1 = ((const float4*)(s + (size_t)i * 8))[1];
    ushort4 h0, h1;
    h0.x = f2h(v0.x); h0.y = f2h(v0.y); h0.z = f2h(v0.z); h0.w = f2h(v0.w);
    h1.x = f2h(v1.x); h1.y = f2h(v1.y); h1.z = f2h(v1.z); h1.w = f2h(v1.w);
    unsigned short* dst = d + (size_t)i * 8;
    *(ushort4*)dst       = h0;
    *(ushort4*)(dst + 4) = h1;
}

// ---------------------------------------------------------------------------
// LayerNorm -> fp16. One block/row, one float4/thread.
// ---------------------------------------------------------------------------
__global__ __launch_bounds__(256) void ln_f16(
    const float* __restrict__ x, const float* __restrict__ g,
    const float* __restrict__ b, unsigned short* __restrict__ y)
{
    const int row = blockIdx.x;
    const int t   = threadIdx.x;
    const float4 v = ((const float4*)(x + (size_t)row * DM))[t];

    float s  = v.x + v.y + v.z + v.w;
    float ss = v.x * v.x + v.y * v.y + v.z * v.z + v.w * v.w;
    #pragma unroll
    for (int off = 32; off > 0; off >>= 1) {
        s  += __shfl_xor(s, off);
        ss += __shfl_xor(ss, off);
    }
    __shared__ float sm[8];
    const int wave = t >> 6;
    if ((t & 63) == 0) { sm[wave * 2] = s; sm[wave * 2 + 1] = ss; }
    __syncthreads();
    s  = sm[0] + sm[2] + sm[4] + sm[6];
    ss = sm[1] + sm[3] + sm[5] + sm[7];

    const float mu  = s * (1.0f / DM);
    const float var = ss * (1.0f / DM) - mu * mu;
    const float r   = rsqrtf(var + 1e-5f);

    const float4 gv = ((const float4*)g)[t];
    const float4 bv = ((const float4*)b)[t];
    ushort4 o;
    o.x = f2h((v.x - mu) * r * gv.x + bv.x);
    o.y = f2h((v.y - mu) * r * gv.y + bv.y);
    o.z = f2h((v.z - mu) * r * gv.z + bv.z);
    o.w = f2h((v.w - mu) * r * gv.w + bv.w);
    ((ushort4*)(y + (size_t)row * DM))[t] = o;
}

// ---------------------------------------------------------------------------
// attention partial pass + merge (verified R4-R9, unchanged).
// ---------------------------------------------------------------------------
__global__ __launch_bounds__(256) void attn_part(
    const unsigned short* __restrict__ kv, const float* __restrict__ kw,
    float* __restrict__ pm, float* __restrict__ pl, float* __restrict__ ps)
{
    const int blk = blockIdx.x;
    const int bh = blk >> 2, qt = blk & 3;
    const int b = bh >> 4, h = bh & 15;
    const int t = threadIdx.x, e = t & 63, w = t >> 6;
    const int nbase = qt * 256 + w * 64;
    const unsigned short* kp =
        kv + (size_t)b * 1024 * 2048 + (size_t)nbase * 2048 + h * 64 + e;
    const float* kwr = kw + h * 1024 + nbase;

    float m = -1e30f, l = 0.f, s = 0.f;
    #pragma unroll 4
    for (int i = 0; i < 64; ++i) {
        const float kval = h2f(kp[(size_t)i * 2048]);
        const float x    = kval * kwr[i] * 0.125f;
        const float nm   = fmaxf(m, x);
        const float c    = __expf(m - nm);
        const float ex   = __expf(x - nm);
        l = l * c + ex;
        s = s * c + ex * kval;
        m = nm;
    }
    __shared__ float sm[3][256];
    sm[0][t] = m; sm[1][t] = l; sm[2][t] = s;
    __syncthreads();
    if (t < 64) {
        #pragma unroll
        for (int ww = 1; ww < 4; ++ww) {
            const float m2 = sm[0][ww * 64 + e];
            const float l2 = sm[1][ww * 64 + e];
            const float s2 = sm[2][ww * 64 + e];
            const float nm = fmaxf(m, m2);
            const float c1 = __expf(m - nm);
            const float c2 = __expf(m2 - nm);
            l = l * c1 + l2 * c2;
            s = s * c1 + s2 * c2;
            m = nm;
        }
        const int o = blk * 64 + e;
        pm[o] = m; pl[o] = l; ps[o] = s;
    }
}

__global__ __launch_bounds__(64) void attn_merge(
    const float* __restrict__ pm, const float* __restrict__ pl,
    const float* __restrict__ ps, float* __restrict__ gk)
{
    const int bh = blockIdx.x, e = threadIdx.x;
    const int b = bh >> 4, h = bh & 15;
    int o = bh * 4 * 64 + e;
    float m = pm[o], l = pl[o], s = ps[o];
    #pragma unroll
    for (int qt = 1; qt < 4; ++qt) {
        o += 64;
        const float m2 = pm[o], l2 = pl[o], s2 = ps[o];
        const float nm = fmaxf(m, m2);
        const float c1 = __expf(m - nm);
        const float c2 = __expf(m2 - nm);
        l = l * c1 + l2 * c2;
        s = s * c1 + s2 * c2;
        m = nm;
    }
    gk[(size_t)b * DM + h * 64 + e] = s / l;
}

// ---------------------------------------------------------------------------
// v-scale: vq[m][d] = fp16( v16[m][d] * gk[batch][d] ).
// ---------------------------------------------------------------------------
__global__ __launch_bounds__(256) void vscale_f16(
    const unsigned short* __restrict__ kv, const float* __restrict__ gk,
    unsigned short* __restrict__ vq)
{
    const int m = blockIdx.x;
    const int t = threadIdx.x;
    const int b = m >> 10;
    const ushort4 v4 = *(const ushort4*)(kv + (size_t)m * 2048 + 1024 + t * 4);
    const float4  s4 = *(const float4*)(gk + b * DM + t * 4);
    ushort4 o;
    o.x = f2h(h2f(v4.x) * s4.x);
    o.y = f2h(h2f(v4.y) * s4.y);
    o.z = f2h(h2f(v4.z) * s4.z);
    o.w = f2h(h2f(v4.w) * s4.w);
    *(ushort4*)(vq + (size_t)m * DM + t * 4) = o;
}

// ---------------------------------------------------------------------------
// fp16 MFMA GEMM, 8-phase (BN=256) / 4-phase (BN=128) schedule.
// 512 thr = 8 waves. BN=256: waves 2x4, per-wave 128x64, acc[8][4].
// BN=128: waves 4x2, per-wave 64x64, acc[4][4].
// LDS: A[2 slot][2 ks][256 rows][64B] @0 (64KB);
//      B[2 slot][2 ks][BN rows][64B] @65536 (64/32KB).
// Slot = K-tile parity (BK=64; ks = 32-wide half). In-row swizzle:
// LDS[row][slot4] = src chunk slot4^(row&3); frag read chunk q^(row&3).
// Phase: {ds_read quadrant || stage ks-half} barrier; MFMA x16; barrier.
// W is plain row-major [N][K] fp16. OUTM: 0 fp16 out, 2 fp32 out+residual.
// LIN1ACT (BN=256): B rows 0-127 = a-rows n0.., 128-255 = g-rows FFH+n0..;
// epilogue fuses a*relu(g) via LDS xch.
// ---------------------------------------------------------------------------
template <bool LIN1ACT, int OUTM, int BN>
__global__ __launch_bounds__(512, 2) void fgemm3(
    const unsigned short* __restrict__ A,
    const unsigned short* __restrict__ W,
    const float* __restrict__ bias,
    const float* __restrict__ residual,
    float* __restrict__ Cf, unsigned short* __restrict__ Cq,
    int K, int lda, int ldc)
{
    constexpr int MH    = (BN == 256) ? 2 : 1;
    constexpr int MR    = 4 * MH;
    constexpr int WROWS = (BN == 256) ? 128 : 64;
    constexpr int BSLOT = (BN == 256) ? 32768 : 16384;
    constexpr int BKS   = (BN == 256) ? 16384 : 8192;
    __shared__ __align__(16) char lds[65536 + 2 * BSLOT];

    const int t   = threadIdx.x;
    const int wid = t >> 6, L = t & 63;
    const int wm  = (BN == 256) ? (wid >> 2) : (wid >> 1);
    const int wn  = (BN == 256) ? (wid & 3)  : (wid & 1);
    const int fr  = L & 15, q = L >> 4;
    const int m0  = blockIdx.y * 256;
    const int n0  = blockIdx.x * (LIN1ACT ? 128 : BN);

    // staging: thread t covers (row = t>>2 [+128 for 2nd event], chunk t&3);
    // source chunk = (t&3)^(row&3) so frag chunk q holds source octet q.
    const int srow = t >> 2;
    const int sch  = (t & 3) ^ (srow & 3);
    const unsigned short* pA4  = A + (size_t)(m0 + srow) * lda + sch * 8;
    const int bn1 = LIN1ACT ? (FFH + n0) : (n0 + 128);
    const unsigned short* pB4a = W + (size_t)(n0 + srow) * K + sch * 8;
    const unsigned short* pB4b = W + (size_t)(bn1 + srow) * K + sch * 8;

    int aoff[MH][4], boff[4];
    #pragma unroll
    for (int mh = 0; mh < MH; ++mh)
        #pragma unroll
        for (int r = 0; r < 4; ++r) {
            const int row = wm * WROWS + mh * 64 + r * 16 + fr;
            aoff[mh][r] = row * 64 + ((q ^ (row & 3)) << 4);
        }
    #pragma unroll
    for (int n = 0; n < 4; ++n) {
        const int col = wn * 64 + n * 16 + fr;
        boff[n] = col * 64 + ((q ^ (col & 3)) << 4);
    }

    f32x4 acc[MR][4];
    #pragma unroll
    for (int i = 0; i < MR; ++i)
        #pragma unroll
        for (int j = 0; j < 4; ++j) acc[i][j] = (f32x4){0.f, 0.f, 0.f, 0.f};
    f16x8 av[4], bv[4];

#define SGA(par, T, ks) do {                                                  \
        gl2lds16(pA4 + (size_t)(T) * 64 + (ks) * 32,                          \
                 lds + (par) * 32768 + (ks) * 16384 + t * 16);                \
        gl2lds16(pA4 + (size_t)128 * lda + (size_t)(T) * 64 + (ks) * 32,      \
                 lds + (par) * 32768 + (ks) * 16384 + 8192 + t * 16);         \
    } while (0)
#define SGB(par, T, ks) do {                                                  \
        gl2lds16(pB4a + (size_t)(T) * 64 + (ks) * 32,                         \
                 lds + 65536 + (par) * BSLOT + (ks) * BKS + t * 16);          \
        if constexpr (BN == 256)                                              \
            gl2lds16(pB4b + (size_t)(T) * 64 + (ks) * 32,                     \
                     lds + 65536 + (par) * BSLOT + (ks) * BKS + 8192 + t * 16);\
    } while (0)
#define RDA(par, ks, mh) do {                                                 \
        const char* ab_ = lds + (par) * 32768 + (ks) * 16384;                 \
        _Pragma("unroll")                                                     \
        for (int r_ = 0; r_ < 4; ++r_)                                        \
            av[r_] = *(const f16x8*)(ab_ + aoff[mh][r_]);                     \
    } while (0)
#define RDB(par, ks) do {                                                     \
        const char* bb_ = lds + 65536 + (par) * BSLOT + (ks) * BKS;           \
        _Pragma("unroll")                                                     \
        for (int n_ = 0; n_ < 4; ++n_)                                        \
            bv[n_] = *(const f16x8*)(bb_ + boff[n_]);                         \
    } while (0)
#define MM(mh) do {                                                           \
        __builtin_amdgcn_s_setprio(1);                                        \
        _Pragma("unroll")                                                     \
        for (int r_ = 0; r_ < 4; ++r_)                                        \
            _Pragma("unroll")                                                 \
            for (int n_ = 0; n_ < 4; ++n_)                                    \
                acc[(mh) * 4 + r_][n_] =                                      \
                    __builtin_amdgcn_mfma_f32_16x16x32_f16(                   \
                        av[r_], bv[n_], acc[(mh) * 4 + r_][n_], 0, 0, 0);     \
        __builtin_amdgcn_s_setprio(0);                                        \
    } while (0)
#define BARR asm volatile("s_barrier" ::: "memory")
#define SB0  __builtin_amdgcn_sched_barrier(0)
#define VMW(S) asm volatile("s_waitcnt vmcnt(" S ")" ::: "memory")

    const int ITERS = K >> 7;   // 2 K-tiles per iteration

    // prologue: t0 (slot0) both ks halves, t1 (slot1) ks0.
    SGA(0, 0, 0); SGB(0, 0, 0);
    SGA(0, 0, 1); SGB(0, 0, 1);
    SGA(1, 1, 0); SGB(1, 1, 0);
    if constexpr (BN == 256) VMW("8"); else VMW("6");
    BARR;

    for (int it = 0; it < ITERS; ++it) {
        const int T1 = 2 * it + 1, T2 = 2 * it + 2, T3 = 2 * it + 3;
        const bool st = (it + 1 < ITERS);
        if constexpr (BN == 256) {
            // ph0: Q(t0,ks0,mh0)
            RDA(0, 0, 0); RDB(0, 0);
            SGA(1, T1, 1);
            BARR; SB0; MM(0); SB0; BARR;
            // ph1: Q(t0,ks0,mh1)
            RDA(0, 0, 1);
            SGB(1, T1, 1);
            VMW("8");
            BARR; SB0; MM(1); SB0; BARR;
            // ph2: Q(t0,ks1,mh0)
            RDA(0, 1, 0); RDB(0, 1);
            if (st) SGA(0, T2, 0);
            BARR; SB0; MM(0); SB0; BARR;
            // ph3: Q(t0,ks1,mh1)
            RDA(0, 1, 1);
            if (st) { SGB(0, T2, 0); VMW("8"); } else { VMW("4"); }
            BARR; SB0; MM(1); SB0; BARR;
            // ph4: Q(t1,ks0,mh0)
            RDA(1, 0, 0); RDB(1, 0);
            if (st) SGA(0, T2, 1);
            BARR; SB0; MM(0); SB0; BARR;
            // ph5: Q(t1,ks0,mh1)
            RDA(1, 0, 1);
            if (st) { SGB(0, T2, 1); VMW("8"); } else { VMW("0"); }
            BARR; SB0; MM(1); SB0; BARR;
            // ph6: Q(t1,ks1,mh0)
            RDA(1, 1, 0); RDB(1, 1);
            if (st) SGA(1, T3, 0);
            BARR; SB0; MM(0); SB0; BARR;
            // ph7: Q(t1,ks1,mh1)
            RDA(1, 1, 1);
            if (st) { SGB(1, T3, 0); VMW("8"); }
            BARR; SB0; MM(1); SB0; BARR;
        } else {
            // ph0: Q(t0,ks0)
            RDA(0, 0, 0); RDB(0, 0);
            SGA(1, T1, 1); SGB(1, T1, 1);
            VMW("6");
            BARR; SB0; MM(0); SB0; BARR;
            // ph1: Q(t0,ks1)
            RDA(0, 1, 0); RDB(0, 1);
            if (st) { SGA(0, T2, 0); SGB(0, T2, 0); VMW("6"); }
            else    { VMW("3"); }
            BARR; SB0; MM(0); SB0; BARR;
            // ph2: Q(t1,ks0)
            RDA(1, 0, 0); RDB(1, 0);
            if (st) { SGA(0, T2, 1); SGB(0, T2, 1); VMW("6"); }
            else    { VMW("0"); }
            BARR; SB0; MM(0); SB0; BARR;
            // ph3: Q(t1,ks1)
            RDA(1, 1, 0); RDB(1, 1);
            if (st) { SGA(1, T3, 0); SGB(1, T3, 0); VMW("6"); }
            BARR; SB0; MM(0); SB0; BARR;
        }
    }
#undef SGA
#undef SGB
#undef RDA
#undef RDB
#undef MM
#undef BARR
#undef SB0
#undef VMW

    if constexpr (!LIN1ACT) {
        #pragma unroll
        for (int mi = 0; mi < MR; ++mi)
            #pragma unroll
            for (int ni = 0; ni < 4; ++ni) {
                const int gcol = n0 + wn * 64 + ni * 16 + fr;
                const float bc = bias[gcol];
                #pragma unroll
                for (int r = 0; r < 4; ++r) {
                    const int grow = m0 + wm * WROWS + mi * 16 + q * 4 + r;
                    float v = acc[mi][ni][r] + bc;
                    if constexpr (OUTM == 2) {
                        v += residual[(size_t)grow * ldc + gcol];
                        Cf[(size_t)grow * ldc + gcol] = v;
                    } else {
                        Cq[(size_t)grow * ldc + gcol] = f2h(v);
                    }
                }
            }
    } else {
        // a*relu(g): waves wn>=2 hold g (frag cols 128..255), push relu(g)
        // through LDS; waves wn<2 hold a, multiply and store.
        unsigned short* xch = (unsigned short*)lds;   // [256][128] fp16 = 64KB
        if (wn >= 2) {
            #pragma unroll
            for (int mi = 0; mi < MR; ++mi)
                #pragma unroll
                for (int ni = 0; ni < 4; ++ni) {
                    const int pc = (wn - 2) * 64 + ni * 16 + fr;
                    const float bg = bias[FFH + n0 + pc];
                    #pragma unroll
                    for (int r = 0; r < 4; ++r) {
                        const int row = wm * WROWS + mi * 16 + q * 4 + r;
                        xch[row * 128 + pc] =
                            f2h(fmaxf(acc[mi][ni][r] + bg, 0.f));
                    }
                }
        }
        __syncthreads();
        if (wn < 2) {
            #pragma unroll
            for (int mi = 0; mi < MR; ++mi)
                #pragma unroll
                for (int ni = 0; ni < 4; ++ni) {
                    const int pc = wn * 64 + ni * 16 + fr;
                    const float ba = bias[n0 + pc];
                    #pragma unroll
                    for (int r = 0; r < 4; ++r) {
                        const int row = wm * WROWS + mi * 16 + q * 4 + r;
                        const float a = acc[mi][ni][r] + ba;
                        const float o = a * h2f(xch[row * 128 + pc]);
                        Cq[(size_t)(m0 + row) * FFH + n0 + pc] = f2h(o);
                    }
                }
        }
    }
}

// ---------------------------------------------------------------------------
extern "C" void kernel_launch(void* const* d_in, const int* in_sizes, int n_in,
                              void* d_out, int out_size, void* d_ws, size_t ws_size,
                              hipStream_t stream)
{
    const float* hidden = (const float*)d_in[0];
    const float* qkv_w  = (const float*)d_in[2];
    const float* qkv_b  = (const float*)d_in[3];
    const float* out_w  = (const float*)d_in[4];
    const float* out_b  = (const float*)d_in[5];
    const float* key_w  = (const float*)d_in[7];
    const float* n1g    = (const float*)d_in[8];
    const float* n1b    = (const float*)d_in[9];
    const float* n2g    = (const float*)d_in[10];
    const float* n2b    = (const float*)d_in[11];
    const float* l1w    = (const float*)d_in[12];
    const float* l1b    = (const float*)d_in[13];
    const float* l2w    = (const float*)d_in[14];
    const float* l2b    = (const float*)d_in[15];
    float* out = (float*)d_out;
    char*  wsb = (char*)d_ws;

    const size_t MB = 1u << 20;
    unsigned short* h16   = (unsigned short*)wsb;               // 16 MB
    unsigned short* kv16  = (unsigned short*)(wsb + 16 * MB);   // 32 MB
    unsigned short* act16 = (unsigned short*)(wsb + 16 * MB);   // overlay
    unsigned short* vq    = (unsigned short*)(wsb + 48 * MB);   // 16 MB
    unsigned short* wkv16 = (unsigned short*)(wsb + 64 * MB);   // 4 MB
    unsigned short* wo16  = (unsigned short*)(wsb + 68 * MB);   // 2 MB
    unsigned short* l116  = (unsigned short*)(wsb + 70 * MB);   // 8 MB
    unsigned short* l216  = (unsigned short*)(wsb + 78 * MB);   // 4 MB
    float*          gk    = (float*)(wsb + 82 * MB);            // 32 KB
    float*          pm    = (float*)(wsb + 83 * MB);            // 128 KB
    float*          pl    = (float*)(wsb + 83 * MB + 131072);
    float*          ps    = (float*)(wsb + 83 * MB + 262144);

    // 0. weights -> fp16, plain row-major
    wcast<<<4608, 256, 0, stream>>>(
        qkv_w + (size_t)DM * DM, out_w, l1w, l2w,
        wkv16, wo16, l116, l216);

    // 1. h1 = LN1(hidden) -> fp16
    ln_f16<<<M_TOT, 256, 0, stream>>>(hidden, n1g, n1b, h16);

    // 2. kv16 = fp16( h1 @ Wkv^T + b )  (ldc 2048), 256 blocks
    fgemm3<false, 0, 256><<<dim3(8, 32), 512, 0, stream>>>(
        h16, wkv16, qkv_b + DM, nullptr, nullptr, kv16, 1024, 1024, 2048);

    // 3. global_key (partial + merge)
    attn_part<<<512, 256, 0, stream>>>(kv16, key_w, pm, pl, ps);
    attn_merge<<<128, 64, 0, stream>>>(pm, pl, ps, gk);

    // 4. vq = fp16(v * gk)
    vscale_f16<<<M_TOT, 256, 0, stream>>>(kv16, gk, vq);

    // 5. hidden2 = hidden + vq @ out_w^T + out_b -> d_out, 256 blocks
    fgemm3<false, 2, 128><<<dim3(8, 32), 512, 0, stream>>>(
        vq, wo16, out_b, hidden, out, nullptr, 1024, 1024, 1024);

    // 6. h2 = LN2(hidden2) -> fp16
    ln_f16<<<M_TOT, 256, 0, stream>>>(out, n2g, n2b, h16);

    // 7. act16 = fp16( (h2@W_a^T+b_a) * relu(h2@W_g^T+b_g) ), 512 blocks
    fgemm3<true, 0, 256><<<dim3(16, 32), 512, 0, stream>>>(
        h16, l116, l1b, nullptr, nullptr, act16, 1024, 1024, 0);

    // 8. out = hidden2 + act @ l2w^T + l2b (in-place residual), 256 blocks
    fgemm3<false, 2, 128><<<dim3(8, 32), 512, 0, stream>>>(
        act16, l216, l2b, out, out, nullptr, 2048, 2048, 1024);
}

// Round 4
// 353.577 us; speedup vs baseline: 1.0473x; 1.0473x over previous
//
#include <hip/hip_runtime.h>
#include <math.h>

// ---------------------------------------------------------------------------
// Fastformer encoder layer — Round 11: fine phases + the validated LDS layout.
//
// R10 post-mortem: 8-phase schedule was correct but the 64B-row ks-split LDS
// layout broke banking (row*16%32 aliases, chunk XOR spans 4) -> 7.3M bank
// conflicts, MfmaUtil 34%. R11 = R10's phase/vmcnt machinery on R9's
// conflict-free 128B-row layout (row*32%32==0, chunk=q^(row&7) spans 8):
//  * A[2 slot][256r][128B] @0, B[slots][256r|128r][128B] @64K. Stage event =
//    8KB = 64 full rows = 1 gl2lds/thread.
//  * BN=256: 4 phases/K-tile {RD frags || stage 3/3/2/0 events -> barrier ->
//    setprio+16 MFMA -> barrier}; vmcnt(3)@ph0, vmcnt(2)@ph3 (derived:
//    exactly covers each consumed event with 2-3 phase slack; floor 2).
//  * BN=128 (N=1024 GEMMs): 2 phases/K-tile, B gets 3 slots (112KB total)
//    so B(T+1) is staged 2 tiles ahead -> per-tile wait is vmcnt(2), no
//    drain except the tail.
// ws: h16@0 | kv16/act16@16M | vq@48M | fp16 weights@64M | gk@82M | attn@83M
// ---------------------------------------------------------------------------

#define DM     1024
#define FFH    2048
#define M_TOT  8192

typedef _Float16 f16x8 __attribute__((ext_vector_type(8)));
typedef float    f32x4 __attribute__((ext_vector_type(4)));

__device__ __forceinline__ void gl2lds16(const void* g, void* l) {
    __builtin_amdgcn_global_load_lds(
        (const __attribute__((address_space(1))) void*)g,
        (__attribute__((address_space(3))) void*)l, 16, 0, 0);
}
__device__ __forceinline__ unsigned short f2h(float x) {
    union { _Float16 h; unsigned short u; } c;
    c.h = (_Float16)x;
    return c.u;
}
__device__ __forceinline__ float h2f(unsigned short u) {
    union { unsigned short u; _Float16 h; } c;
    c.u = u;
    return (float)c.h;
}

// ---------------------------------------------------------------------------
// weight cast fp32 -> fp16, plain row-major, fully coalesced.
// ---------------------------------------------------------------------------
__global__ __launch_bounds__(256) void wcast(
    const float* __restrict__ s0, const float* __restrict__ s1,
    const float* __restrict__ s2, const float* __restrict__ s3,
    unsigned short* __restrict__ d0, unsigned short* __restrict__ d1,
    unsigned short* __restrict__ d2, unsigned short* __restrict__ d3)
{
    int i = blockIdx.x * 256 + threadIdx.x;
    const float* s; unsigned short* d;
    if      (i < 262144) {               s = s0; d = d0; }
    else if (i < 393216) { i -= 262144;  s = s1; d = d1; }
    else if (i < 917504) { i -= 393216;  s = s2; d = d2; }
    else                 { i -= 917504;  s = s3; d = d3; }
    const float4 v0 = ((const float4*)(s + (size_t)i * 8))[0];
    const float4 v1 = ((const float4*)(s + (size_t)i * 8))[1];
    ushort4 h0, h1;
    h0.x = f2h(v0.x); h0.y = f2h(v0.y); h0.z = f2h(v0.z); h0.w = f2h(v0.w);
    h1.x = f2h(v1.x); h1.y = f2h(v1.y); h1.z = f2h(v1.z); h1.w = f2h(v1.w);
    unsigned short* dst = d + (size_t)i * 8;
    *(ushort4*)dst       = h0;
    *(ushort4*)(dst + 4) = h1;
}

// ---------------------------------------------------------------------------
// LayerNorm -> fp16. One block/row, one float4/thread.
// ---------------------------------------------------------------------------
__global__ __launch_bounds__(256) void ln_f16(
    const float* __restrict__ x, const float* __restrict__ g,
    const float* __restrict__ b, unsigned short* __restrict__ y)
{
    const int row = blockIdx.x;
    const int t   = threadIdx.x;
    const float4 v = ((const float4*)(x + (size_t)row * DM))[t];

    float s  = v.x + v.y + v.z + v.w;
    float ss = v.x * v.x + v.y * v.y + v.z * v.z + v.w * v.w;
    #pragma unroll
    for (int off = 32; off > 0; off >>= 1) {
        s  += __shfl_xor(s, off);
        ss += __shfl_xor(ss, off);
    }
    __shared__ float sm[8];
    const int wave = t >> 6;
    if ((t & 63) == 0) { sm[wave * 2] = s; sm[wave * 2 + 1] = ss; }
    __syncthreads();
    s  = sm[0] + sm[2] + sm[4] + sm[6];
    ss = sm[1] + sm[3] + sm[5] + sm[7];

    const float mu  = s * (1.0f / DM);
    const float var = ss * (1.0f / DM) - mu * mu;
    const float r   = rsqrtf(var + 1e-5f);

    const float4 gv = ((const float4*)g)[t];
    const float4 bv = ((const float4*)b)[t];
    ushort4 o;
    o.x = f2h((v.x - mu) * r * gv.x + bv.x);
    o.y = f2h((v.y - mu) * r * gv.y + bv.y);
    o.z = f2h((v.z - mu) * r * gv.z + bv.z);
    o.w = f2h((v.w - mu) * r * gv.w + bv.w);
    ((ushort4*)(y + (size_t)row * DM))[t] = o;
}

// ---------------------------------------------------------------------------
// attention partial pass + merge (verified R4-R10, unchanged).
// ---------------------------------------------------------------------------
__global__ __launch_bounds__(256) void attn_part(
    const unsigned short* __restrict__ kv, const float* __restrict__ kw,
    float* __restrict__ pm, float* __restrict__ pl, float* __restrict__ ps)
{
    const int blk = blockIdx.x;
    const int bh = blk >> 2, qt = blk & 3;
    const int b = bh >> 4, h = bh & 15;
    const int t = threadIdx.x, e = t & 63, w = t >> 6;
    const int nbase = qt * 256 + w * 64;
    const unsigned short* kp =
        kv + (size_t)b * 1024 * 2048 + (size_t)nbase * 2048 + h * 64 + e;
    const float* kwr = kw + h * 1024 + nbase;

    float m = -1e30f, l = 0.f, s = 0.f;
    #pragma unroll 4
    for (int i = 0; i < 64; ++i) {
        const float kval = h2f(kp[(size_t)i * 2048]);
        const float x    = kval * kwr[i] * 0.125f;
        const float nm   = fmaxf(m, x);
        const float c    = __expf(m - nm);
        const float ex   = __expf(x - nm);
        l = l * c + ex;
        s = s * c + ex * kval;
        m = nm;
    }
    __shared__ float sm[3][256];
    sm[0][t] = m; sm[1][t] = l; sm[2][t] = s;
    __syncthreads();
    if (t < 64) {
        #pragma unroll
        for (int ww = 1; ww < 4; ++ww) {
            const float m2 = sm[0][ww * 64 + e];
            const float l2 = sm[1][ww * 64 + e];
            const float s2 = sm[2][ww * 64 + e];
            const float nm = fmaxf(m, m2);
            const float c1 = __expf(m - nm);
            const float c2 = __expf(m2 - nm);
            l = l * c1 + l2 * c2;
            s = s * c1 + s2 * c2;
            m = nm;
        }
        const int o = blk * 64 + e;
        pm[o] = m; pl[o] = l; ps[o] = s;
    }
}

__global__ __launch_bounds__(64) void attn_merge(
    const float* __restrict__ pm, const float* __restrict__ pl,
    const float* __restrict__ ps, float* __restrict__ gk)
{
    const int bh = blockIdx.x, e = threadIdx.x;
    const int b = bh >> 4, h = bh & 15;
    int o = bh * 4 * 64 + e;
    float m = pm[o], l = pl[o], s = ps[o];
    #pragma unroll
    for (int qt = 1; qt < 4; ++qt) {
        o += 64;
        const float m2 = pm[o], l2 = pl[o], s2 = ps[o];
        const float nm = fmaxf(m, m2);
        const float c1 = __expf(m - nm);
        const float c2 = __expf(m2 - nm);
        l = l * c1 + l2 * c2;
        s = s * c1 + s2 * c2;
        m = nm;
    }
    gk[(size_t)b * DM + h * 64 + e] = s / l;
}

// ---------------------------------------------------------------------------
// v-scale: vq[m][d] = fp16( v16[m][d] * gk[batch][d] ).
// ---------------------------------------------------------------------------
__global__ __launch_bounds__(256) void vscale_f16(
    const unsigned short* __restrict__ kv, const float* __restrict__ gk,
    unsigned short* __restrict__ vq)
{
    const int m = blockIdx.x;
    const int t = threadIdx.x;
    const int b = m >> 10;
    const ushort4 v4 = *(const ushort4*)(kv + (size_t)m * 2048 + 1024 + t * 4);
    const float4  s4 = *(const float4*)(gk + b * DM + t * 4);
    ushort4 o;
    o.x = f2h(h2f(v4.x) * s4.x);
    o.y = f2h(h2f(v4.y) * s4.y);
    o.z = f2h(h2f(v4.z) * s4.z);
    o.w = f2h(h2f(v4.w) * s4.w);
    *(ushort4*)(vq + (size_t)m * DM + t * 4) = o;
}

// ---------------------------------------------------------------------------
// fp16 MFMA GEMM. 512 thr = 8 waves, 256-row block tile.
// BN=256: waves 2x4, per-wave 128x64, acc[8][4], 4 phases/K-tile, B 2 slots.
// BN=128: waves 4x2, per-wave  64x64, acc[4][4], 2 phases/K-tile, B 3 slots.
// LDS rows are 128B (BK=64 fp16): conflict-free validated layout.
//   stage:  row = t>>3, chunk (t&7) holds source chunk (t&7)^(row&7)
//   frags:  addr = row*128 + ((q^(row&7))<<4), ks toggles ^64
// W plain row-major [N][K] fp16. OUTM: 0 fp16 out, 2 fp32 out + residual.
// LIN1ACT (BN=256): B rows = {a: n0..+127, g: FFH+n0..+127}; epilogue fuses
// a*relu(g) via LDS xch.
// ---------------------------------------------------------------------------
template <bool LIN1ACT, int OUTM, int BN>
__global__ __launch_bounds__(512, 2) void fgemm4(
    const unsigned short* __restrict__ A,
    const unsigned short* __restrict__ W,
    const float* __restrict__ bias,
    const float* __restrict__ residual,
    float* __restrict__ Cf, unsigned short* __restrict__ Cq,
    int K, int lda, int ldc)
{
    constexpr int MH    = (BN == 256) ? 2 : 1;
    constexpr int MR    = 4 * MH;
    constexpr int WROWS = (BN == 256) ? 128 : 64;
    constexpr int NBEV  = (BN == 256) ? 4 : 2;     // B stage events per tile
    constexpr int BSLOT = (BN == 256) ? 32768 : 16384;
    constexpr int NBS   = (BN == 256) ? 2 : 3;     // B slots
    __shared__ __align__(16) char lds[65536 + NBS * BSLOT];

    const int t   = threadIdx.x;
    const int wid = t >> 6, L = t & 63;
    const int wm  = (BN == 256) ? (wid >> 2) : (wid >> 1);
    const int wn  = (BN == 256) ? (wid & 3)  : (wid & 1);
    const int fr  = L & 15, q = L >> 4;
    const int m0  = blockIdx.y * 256;
    const int n0  = blockIdx.x * (LIN1ACT ? 128 : BN);

    // staging pointers (validated layout)
    const int srow = t >> 3;
    const int sch  = (t & 7) ^ (srow & 7);
    const unsigned short* pA = A + (size_t)(m0 + srow) * lda + sch * 8;
    const unsigned short* pB = W + (size_t)(n0 + srow) * K + sch * 8;
    size_t browOff[NBEV];
    #pragma unroll
    for (int j = 0; j < NBEV; ++j) {
        int rel;
        if (LIN1ACT) rel = (j < 2) ? (64 * j) : (FFH + 64 * (j - 2));
        else         rel = 64 * j;
        browOff[j] = (size_t)rel * K;
    }

    // fragment read offsets
    int aoff[MH][4], boff[4];
    #pragma unroll
    for (int mh = 0; mh < MH; ++mh)
        #pragma unroll
        for (int r = 0; r < 4; ++r) {
            const int row = wm * WROWS + mh * 64 + r * 16 + fr;
            aoff[mh][r] = row * 128 + ((q ^ (row & 7)) << 4);
        }
    #pragma unroll
    for (int n = 0; n < 4; ++n) {
        const int col = wn * 64 + n * 16 + fr;
        boff[n] = col * 128 + ((q ^ (col & 7)) << 4);
    }

    f32x4 acc[MR][4];
    #pragma unroll
    for (int i = 0; i < MR; ++i)
        #pragma unroll
        for (int j = 0; j < 4; ++j) acc[i][j] = (f32x4){0.f, 0.f, 0.f, 0.f};
    f16x8 av[4], bv[4];

#define SGA(par, j, ko) gl2lds16(pA + (size_t)(j) * 64 * lda + (ko),          \
                                 lds + (par) * 32768 + (j) * 8192 + t * 16)
#define SGB(sl, j, ko)  gl2lds16(pB + browOff[j] + (ko),                      \
                                 lds + 65536 + (sl) * BSLOT + (j) * 8192 +    \
                                 t * 16)
#define RDA(par, ks, mh) do {                                                 \
        const char* ab_ = lds + (par) * 32768;                                \
        _Pragma("unroll")                                                     \
        for (int r_ = 0; r_ < 4; ++r_)                                        \
            av[r_] = *(const f16x8*)(ab_ + (aoff[mh][r_] ^ ((ks) * 64)));     \
    } while (0)
#define RDB(sl, ks) do {                                                      \
        const char* bb_ = lds + 65536 + (sl) * BSLOT;                         \
        _Pragma("unroll")                                                     \
        for (int n_ = 0; n_ < 4; ++n_)                                        \
            bv[n_] = *(const f16x8*)(bb_ + (boff[n_] ^ ((ks) * 64)));         \
    } while (0)
#define MM(mh) do {                                                           \
        __builtin_amdgcn_s_setprio(1);                                        \
        _Pragma("unroll")                                                     \
        for (int r_ = 0; r_ < 4; ++r_)                                        \
            _Pragma("unroll")                                                 \
            for (int n_ = 0; n_ < 4; ++n_)                                    \
                acc[(mh) * 4 + r_][n_] =                                      \
                    __builtin_amdgcn_mfma_f32_16x16x32_f16(                   \
                        av[r_], bv[n_], acc[(mh) * 4 + r_][n_], 0, 0, 0);     \
        __builtin_amdgcn_s_setprio(0);                                        \
    } while (0)
#define BARR asm volatile("s_barrier" ::: "memory")
#define SB0  __builtin_amdgcn_sched_barrier(0)
#define VMW0 asm volatile("s_waitcnt vmcnt(0)" ::: "memory")
#define VMW2 asm volatile("s_waitcnt vmcnt(2)" ::: "memory")
#define VMW3 asm volatile("s_waitcnt vmcnt(3)" ::: "memory")

    const int KT = K >> 6;

    if constexpr (BN == 256) {
        // prologue: tile 0 -> slot 0 (8 events), drain once.
        SGB(0, 0, 0); SGB(0, 1, 0); SGB(0, 2, 0); SGB(0, 3, 0);
        SGA(0, 0, 0); SGA(0, 1, 0); SGA(0, 2, 0); SGA(0, 3, 0);
        VMW0; BARR;
        for (int T = 0; T < KT; ++T) {
            const int  s = T & 1, ns = s ^ 1;
            const bool st = (T + 1 < KT);
            const int  ko = (T + 1) << 6;
            // ph0: quadrant (ks0,mh0); stage B0-2(T+1); wait A1,A3(T)
            RDA(s, 0, 0); RDB(s, 0);
            if (st) { SGB(ns, 0, ko); SGB(ns, 1, ko); SGB(ns, 2, ko); VMW3; }
            else    { VMW0; }
            BARR; SB0; MM(0); SB0; BARR;
            // ph1: (ks0,mh1); stage B3,A0,A2(T+1)
            RDA(s, 0, 1);
            if (st) { SGB(ns, 3, ko); SGA(ns, 0, ko); SGA(ns, 2, ko); }
            BARR; SB0; MM(1); SB0; BARR;
            // ph2: (ks1,mh0); stage A1,A3(T+1)
            RDA(s, 1, 0); RDB(s, 1);
            if (st) { SGA(ns, 1, ko); SGA(ns, 3, ko); }
            BARR; SB0; MM(0); SB0; BARR;
            // ph3: (ks1,mh1); wait B0-3,A0,A2(T+1) (2 youngest may fly)
            RDA(s, 1, 1);
            if (st) VMW2;
            BARR; SB0; MM(1); SB0; BARR;
        }
    } else {
        // prologue: A(T0)->slot0, B(T0)->bs0, B(T1)->bs1; drain once.
        SGA(0, 0, 0); SGA(0, 1, 0); SGA(0, 2, 0); SGA(0, 3, 0);
        SGB(0, 0, 0); SGB(0, 1, 0);
        SGB(1, 0, 64); SGB(1, 1, 64);
        VMW0; BARR;
        int bs = 0;
        for (int T = 0; T < KT; ++T) {
            const int  sA = T & 1, nsA = sA ^ 1;
            const bool st1 = (T + 1 < KT), st2 = (T + 2 < KT);
            const int  ko1 = (T + 1) << 6, ko2 = (T + 2) << 6;
            int bs2 = bs + 2; if (bs2 >= 3) bs2 -= 3;
            // ph0: ks0; stage A(T+1) (4 events)
            RDA(sA, 0, 0); RDB(bs, 0);
            if (st1) { SGA(nsA, 0, ko1); SGA(nsA, 1, ko1);
                       SGA(nsA, 2, ko1); SGA(nsA, 3, ko1); }
            BARR; SB0; MM(0); SB0; BARR;
            // ph1: ks1; stage B(T+2) (2 events); wait A(T+1),B(T+1)
            RDA(sA, 1, 0); RDB(bs, 1);
            if (st2)      { SGB(bs2, 0, ko2); SGB(bs2, 1, ko2); VMW2; }
            else if (st1) { VMW0; }
            BARR; SB0; MM(0); SB0; BARR;
            if (++bs == 3) bs = 0;
        }
    }
#undef SGA
#undef SGB
#undef RDA
#undef RDB
#undef MM
#undef BARR
#undef SB0
#undef VMW0
#undef VMW2
#undef VMW3

    if constexpr (!LIN1ACT) {
        #pragma unroll
        for (int mi = 0; mi < MR; ++mi)
            #pragma unroll
            for (int ni = 0; ni < 4; ++ni) {
                const int gcol = n0 + wn * 64 + ni * 16 + fr;
                const float bc = bias[gcol];
                #pragma unroll
                for (int r = 0; r < 4; ++r) {
                    const int grow = m0 + wm * WROWS + mi * 16 + q * 4 + r;
                    float v = acc[mi][ni][r] + bc;
                    if constexpr (OUTM == 2) {
                        v += residual[(size_t)grow * ldc + gcol];
                        Cf[(size_t)grow * ldc + gcol] = v;
                    } else {
                        Cq[(size_t)grow * ldc + gcol] = f2h(v);
                    }
                }
            }
    } else {
        // a*relu(g): waves wn>=2 hold g (B rows 128-255), push relu(g)
        // through LDS; waves wn<2 hold a, multiply and store.
        unsigned short* xch = (unsigned short*)lds;   // [256][128] fp16 = 64KB
        if (wn >= 2) {
            #pragma unroll
            for (int mi = 0; mi < MR; ++mi)
                #pragma unroll
                for (int ni = 0; ni < 4; ++ni) {
                    const int pc = (wn - 2) * 64 + ni * 16 + fr;
                    const float bg = bias[FFH + n0 + pc];
                    #pragma unroll
                    for (int r = 0; r < 4; ++r) {
                        const int row = wm * WROWS + mi * 16 + q * 4 + r;
                        xch[row * 128 + pc] =
                            f2h(fmaxf(acc[mi][ni][r] + bg, 0.f));
                    }
                }
        }
        __syncthreads();
        if (wn < 2) {
            #pragma unroll
            for (int mi = 0; mi < MR; ++mi)
                #pragma unroll
                for (int ni = 0; ni < 4; ++ni) {
                    const int pc = wn * 64 + ni * 16 + fr;
                    const float ba = bias[n0 + pc];
                    #pragma unroll
                    for (int r = 0; r < 4; ++r) {
                        const int row = wm * WROWS + mi * 16 + q * 4 + r;
                        const float a = acc[mi][ni][r] + ba;
                        const float o = a * h2f(xch[row * 128 + pc]);
                        Cq[(size_t)(m0 + row) * FFH + n0 + pc] = f2h(o);
                    }
                }
        }
    }
}

// ---------------------------------------------------------------------------
extern "C" void kernel_launch(void* const* d_in, const int* in_sizes, int n_in,
                              void* d_out, int out_size, void* d_ws, size_t ws_size,
                              hipStream_t stream)
{
    const float* hidden = (const float*)d_in[0];
    const float* qkv_w  = (const float*)d_in[2];
    const float* qkv_b  = (const float*)d_in[3];
    const float* out_w  = (const float*)d_in[4];
    const float* out_b  = (const float*)d_in[5];
    const float* key_w  = (const float*)d_in[7];
    const float* n1g    = (const float*)d_in[8];
    const float* n1b    = (const float*)d_in[9];
    const float* n2g    = (const float*)d_in[10];
    const float* n2b    = (const float*)d_in[11];
    const float* l1w    = (const float*)d_in[12];
    const float* l1b    = (const float*)d_in[13];
    const float* l2w    = (const float*)d_in[14];
    const float* l2b    = (const float*)d_in[15];
    float* out = (float*)d_out;
    char*  wsb = (char*)d_ws;

    const size_t MB = 1u << 20;
    unsigned short* h16   = (unsigned short*)wsb;               // 16 MB
    unsigned short* kv16  = (unsigned short*)(wsb + 16 * MB);   // 32 MB
    unsigned short* act16 = (unsigned short*)(wsb + 16 * MB);   // overlay
    unsigned short* vq    = (unsigned short*)(wsb + 48 * MB);   // 16 MB
    unsigned short* wkv16 = (unsigned short*)(wsb + 64 * MB);   // 4 MB
    unsigned short* wo16  = (unsigned short*)(wsb + 68 * MB);   // 2 MB
    unsigned short* l116  = (unsigned short*)(wsb + 70 * MB);   // 8 MB
    unsigned short* l216  = (unsigned short*)(wsb + 78 * MB);   // 4 MB
    float*          gk    = (float*)(wsb + 82 * MB);            // 32 KB
    float*          pm    = (float*)(wsb + 83 * MB);            // 128 KB
    float*          pl    = (float*)(wsb + 83 * MB + 131072);
    float*          ps    = (float*)(wsb + 83 * MB + 262144);

    // 0. weights -> fp16, plain row-major
    wcast<<<4608, 256, 0, stream>>>(
        qkv_w + (size_t)DM * DM, out_w, l1w, l2w,
        wkv16, wo16, l116, l216);

    // 1. h1 = LN1(hidden) -> fp16
    ln_f16<<<M_TOT, 256, 0, stream>>>(hidden, n1g, n1b, h16);

    // 2. kv16 = fp16( h1 @ Wkv^T + b )  (ldc 2048), 256 blocks
    fgemm4<false, 0, 256><<<dim3(8, 32), 512, 0, stream>>>(
        h16, wkv16, qkv_b + DM, nullptr, nullptr, kv16, 1024, 1024, 2048);

    // 3. global_key (partial + merge)
    attn_part<<<512, 256, 0, stream>>>(kv16, key_w, pm, pl, ps);
    attn_merge<<<128, 64, 0, stream>>>(pm, pl, ps, gk);

    // 4. vq = fp16(v * gk)
    vscale_f16<<<M_TOT, 256, 0, stream>>>(kv16, gk, vq);

    // 5. hidden2 = hidden + vq @ out_w^T + out_b -> d_out, 256 blocks
    fgemm4<false, 2, 128><<<dim3(8, 32), 512, 0, stream>>>(
        vq, wo16, out_b, hidden, out, nullptr, 1024, 1024, 1024);

    // 6. h2 = LN2(hidden2) -> fp16
    ln_f16<<<M_TOT, 256, 0, stream>>>(out, n2g, n2b, h16);

    // 7. act16 = fp16( (h2@W_a^T+b_a) * relu(h2@W_g^T+b_g) ), 512 blocks
    fgemm4<true, 0, 256><<<dim3(16, 32), 512, 0, stream>>>(
        h16, l116, l1b, nullptr, nullptr, act16, 1024, 1024, 0);

    // 8. out = hidden2 + act @ l2w^T + l2b (in-place residual), 256 blocks
    fgemm4<false, 2, 128><<<dim3(8, 32), 512, 0, stream>>>(
        act16, l216, l2b, out, out, nullptr, 2048, 2048, 1024);
}